// Round 14
// baseline (513.969 us; speedup 1.0000x reference)
//
#include <hip/hip_runtime.h>
#include <hip/hip_bf16.h>
#include <stdint.h>

#define B_ 4
#define T_ 2048
#define D_ 1024
#define H_ 16
#define DK_ 64
#define LOG2E 1.44269504088896340736f
#define NEGF (-3.0e38f)

typedef __attribute__((ext_vector_type(8))) short bf16x8;
typedef __attribute__((ext_vector_type(4))) float f32x4;

#define FENCE()   asm volatile("" ::: "memory")
#define SCHEDB()  __builtin_amdgcn_sched_barrier(0)
#define SBAR()    __builtin_amdgcn_s_barrier()
#define WAITV0()  asm volatile("s_waitcnt vmcnt(0)" ::: "memory")
#define WAITL0()  asm volatile("s_waitcnt lgkmcnt(0)" ::: "memory")
#define WAITLV4() asm volatile("s_waitcnt lgkmcnt(0) vmcnt(4)" ::: "memory")

// compiler-native bf16 convert (lowers to v_cvt_pk_bf16_f32 when paired)
__device__ inline unsigned short f2bf(float f){
  union { __hip_bfloat16 h; unsigned short u; } v;
  v.h = __hip_bfloat16(f);
  return v.u;
}
__device__ inline unsigned int pk2(float a, float b){
  return (unsigned int)f2bf(a) | ((unsigned int)f2bf(b) << 16);
}
__device__ inline float fexp2(float x){ return __builtin_amdgcn_exp2f(x); }
__device__ inline f32x4 mfma16(bf16x8 a, bf16x8 b, f32x4 c){
  return __builtin_amdgcn_mfma_f32_16x16x32_bf16(a, b, c, 0, 0, 0);
}
// LDS tile rows = 64 bf16 = 128B = 8 chunks of 16B, chunk swizzle: phys = logical ^ (row&7)
__device__ inline bf16x8 lds_frag(const unsigned short* base, int row, int slot){
  return *(const bf16x8*)((const char*)base + row*128 + ((slot ^ (row & 7)) << 4));
}
// async global->LDS, 16B per lane. LDS dest = wave-uniform base + lane*16 (linear).
__device__ inline void gload16(const void* g, void* l){
  __builtin_amdgcn_global_load_lds((const __attribute__((address_space(1))) void*)g,
                                   (__attribute__((address_space(3))) void*)l, 16, 0, 0);
}
// 128x64 bf16 tile: wave stages 32 rows (4 instrs x 8 rows). Source chunk pre-swizzled.
__device__ inline void stage_gl128(const unsigned short* __restrict__ g, int ld,
                                   unsigned short* lds, int wave, int lane){
#pragma unroll
  for (int i = 0; i < 4; ++i){
    int row = wave*32 + i*8 + (lane >> 3);
    int c = (lane & 7) ^ (row & 7);
    gload16(g + (size_t)row*ld + c*8, lds + (wave*32 + i*8)*64);
  }
}
// 64x64 bf16 tile: wave stages 16 rows (2 VMEM instrs x 8 rows).
__device__ inline void stage_gl64(const unsigned short* __restrict__ g, int ld,
                                  unsigned short* lds, int wave, int lane){
#pragma unroll
  for (int i = 0; i < 2; ++i){
    int row = wave*16 + i*8 + (lane >> 3);
    int c = (lane & 7) ^ (row & 7);
    gload16(g + (size_t)row*ld + c*8, lds + (wave*16 + i*8)*64);
  }
}

// ---------------- mask pack: (B,T,T) int32 -> bitmask u64 ----------------
__global__ void pack_mask_k(const int* __restrict__ mask, unsigned long long* __restrict__ bits){
  int i = blockIdx.x * 256 + threadIdx.x;
  unsigned long long b = __ballot(mask[i] != 0);
  if ((threadIdx.x & 63) == 0) bits[i >> 6] = b;
}

// ---------------- fused fp32->bf16: weights (4x1M) + inputs (3x8M) ----------------
__global__ void convall_k(const float* __restrict__ Wq, const float* __restrict__ Wk,
                          const float* __restrict__ Wv, const float* __restrict__ Wo,
                          const float* __restrict__ q, const float* __restrict__ k,
                          const float* __restrict__ v,
                          unsigned short* __restrict__ wdst, unsigned short* __restrict__ xdst){
  int g = blockIdx.x*256 + threadIdx.x;     // 14336 blocks x 256
  const float* s; unsigned short* d; int off;
  if (g < 524288){
    int w = g >> 17; off = (g & 131071) * 8;
    s = (w==0) ? Wq : (w==1) ? Wk : (w==2) ? Wv : Wo;
    d = wdst + (size_t)w*1048576 + off;
  } else {
    int gg = g - 524288;
    int w = gg >> 20; off = (gg & 1048575) * 8;
    s = (w==0) ? q : (w==1) ? k : v;
    d = xdst + (size_t)w*8388608 + off;
  }
  float4 a = *(const float4*)(s + off);
  float4 b2 = *(const float4*)(s + off + 4);
  uint4 o;
  o.x = pk2(a.x,a.y); o.y = pk2(a.z,a.w); o.z = pk2(b2.x,b2.y); o.w = pk2(b2.z,b2.w);
  *(uint4*)d = o;
}

// ---------------- unified input GEMMs: Q, K + Vt, 1536 blocks (2 full waves @3/CU) ----------------
__global__ __launch_bounds__(256, 3)
void gemm_in(const unsigned short* __restrict__ Xbf, const unsigned short* __restrict__ Wbf,
             const float* __restrict__ bq, const float* __restrict__ bk,
             const float* __restrict__ bv,
             unsigned short* __restrict__ QKout, unsigned short* __restrict__ Vt)
{
  __shared__ __align__(16) unsigned short As[128*64];
  __shared__ __align__(16) unsigned short Bs[128*64];
  const int tid = threadIdx.x, lane = tid & 63, wave = tid >> 6;
  const int lcol = lane & 15, lgrp = lane >> 4;
  const int id = blockIdx.x;
  const bool vmode = (id >= 1024);
  int mtile, ntile;
  const unsigned short *A, *W;
  if (!vmode){
    int z = id >> 9, rem = id & 511;
    mtile = rem >> 3; ntile = rem & 7;
    A = Xbf + (size_t)z*8388608;
    W = Wbf + (size_t)z*1048576;
  } else {
    int rem = id - 1024;
    mtile = rem >> 6; ntile = rem & 63;
    A = Wbf + (size_t)2*1048576;      // Wv
    W = Xbf + (size_t)2*8388608;      // value_bf
  }
  const int wm = (wave & 1) * 64, wn = (wave >> 1) * 64;
  f32x4 acc[4][4] = {};
#pragma unroll 1
  for (int kt = 0; kt < 16; ++kt){
    stage_gl128(A + (size_t)(mtile*128)*1024 + kt*64, 1024, As, wave, lane);
    stage_gl128(W + (size_t)(ntile*128)*1024 + kt*64, 1024, Bs, wave, lane);
    __syncthreads();
    bf16x8 af[4][2], bfr[4][2];
#pragma unroll
    for (int mi=0;mi<4;mi++)
#pragma unroll
      for (int kh=0;kh<2;kh++)
        af[mi][kh] = lds_frag(As, wm + mi*16 + lcol, kh*4 + lgrp);
#pragma unroll
    for (int ni=0;ni<4;ni++)
#pragma unroll
      for (int kh=0;kh<2;kh++)
        bfr[ni][kh] = lds_frag(Bs, wn + ni*16 + lcol, kh*4 + lgrp);
    __builtin_amdgcn_s_setprio(1);
#pragma unroll
    for (int mi=0;mi<4;mi++)
#pragma unroll
      for (int ni=0;ni<4;ni++)
#pragma unroll
        for (int kh=0;kh<2;kh++)
          acc[mi][ni] = mfma16(af[mi][kh], bfr[ni][kh], acc[mi][ni]);
    __builtin_amdgcn_s_setprio(0);
    __syncthreads();
  }
  if (!vmode){
    int z = id >> 9;
    const float* bias = z ? bk : bq;
    unsigned short* C = QKout + (size_t)z*8388608;
    float osc = z ? 1.0f : 0.125f*LOG2E;
#pragma unroll
    for (int mi=0;mi<4;mi++)
#pragma unroll
      for (int ni=0;ni<4;ni++){
        int n = ntile*128 + wn + ni*16 + lcol;
#pragma unroll
        for (int r=0;r<4;r++){
          int m = mtile*128 + wm + mi*16 + lgrp*4 + r;
          float v = (acc[mi][ni][r] + bias[n]) * osc;
          int bb = m >> 11, t = m & 2047, hh = n >> 6, dk = n & 63;
          C[(((size_t)(bb*H_ + hh)*T_ + t) << 6) + dk] = f2bf(v);
        }
      }
  } else {
#pragma unroll
    for (int mi=0;mi<4;mi++)
#pragma unroll
      for (int ni=0;ni<4;ni++){
        int n = ntile*128 + wn + ni*16 + lcol;
#pragma unroll
        for (int r=0;r<4;r++){
          int m = mtile*128 + wm + mi*16 + lgrp*4 + r;
          float v = acc[mi][ni][r] + bv[m];
          int bb = n >> 11, t = n & 2047, hh = m >> 6, dk = m & 63;
          Vt[(((size_t)(bb*H_ + hh)*DK_ + dk) << 11) + t] = f2bf(v);
        }
      }
  }
}

// ---------------- out GEMM: out[8192][1024] = Xq(B,H,T,DK) @ Wo^T + bo (fp32 out) ----------------
__global__ __launch_bounds__(256, 3)
void gemm_out(const unsigned short* __restrict__ A, const unsigned short* __restrict__ W,
              const float* __restrict__ bias, float* __restrict__ C)
{
  __shared__ __align__(16) unsigned short As[128*64];
  __shared__ __align__(16) unsigned short Bs[128*64];
  const int tid = threadIdx.x, lane = tid & 63, wave = tid >> 6;
  const int lcol = lane & 15, lgrp = lane >> 4;
  const int mtile = blockIdx.y, ntile = blockIdx.x;
  const int wm = (wave & 1) * 64, wn = (wave >> 1) * 64;
  f32x4 acc[4][4] = {};
#pragma unroll 1
  for (int kt = 0; kt < 16; ++kt){
    int m0 = mtile*128; int b = m0 >> 11; int t0 = m0 & 2047;
    const unsigned short* xbase = A + (((size_t)(b*16 + kt)*2048 + t0) << 6);
    stage_gl128(xbase, 64, As, wave, lane);
    stage_gl128(W + (size_t)(ntile*128)*1024 + kt*64, 1024, Bs, wave, lane);
    __syncthreads();
    bf16x8 af[4][2], bfr[4][2];
#pragma unroll
    for (int mi=0;mi<4;mi++)
#pragma unroll
      for (int kh=0;kh<2;kh++)
        af[mi][kh] = lds_frag(As, wm + mi*16 + lcol, kh*4 + lgrp);
#pragma unroll
    for (int ni=0;ni<4;ni++)
#pragma unroll
      for (int kh=0;kh<2;kh++)
        bfr[ni][kh] = lds_frag(Bs, wn + ni*16 + lcol, kh*4 + lgrp);
    __builtin_amdgcn_s_setprio(1);
#pragma unroll
    for (int mi=0;mi<4;mi++)
#pragma unroll
      for (int ni=0;ni<4;ni++)
#pragma unroll
        for (int kh=0;kh<2;kh++)
          acc[mi][ni] = mfma16(af[mi][kh], bfr[ni][kh], acc[mi][ni]);
    __builtin_amdgcn_s_setprio(0);
    __syncthreads();
  }
#pragma unroll
  for (int mi=0;mi<4;mi++)
#pragma unroll
    for (int ni=0;ni<4;ni++){
      int n = ntile*128 + wn + ni*16 + lcol;
#pragma unroll
      for (int r=0;r<4;r++){
        int m = mtile*128 + wm + mi*16 + lgrp*4 + r;
        C[(size_t)m*D_ + n] = acc[mi][ni][r] + bias[n];
      }
    }
}

// ---------------- fused attention (S^T, QBLK=64, XCD-local bh) ----------------
// Sweep 1: NO LDS, NO barriers -- K and Q fragments read DIRECTLY from global
// (L2-resident per XCD mapping; LDS-staging cache-fit data is pure overhead).
// Sweep 2: R8/R11 proven structure (LDS dbuf K/V, nt attn stores, counted vmcnt).
__global__ __launch_bounds__(256, 4)
void attn_k(const unsigned short* __restrict__ Qbh, const unsigned short* __restrict__ Kbh,
            const unsigned short* __restrict__ Vt, const unsigned long long* __restrict__ mbits,
            float* __restrict__ attn, unsigned short* __restrict__ Xq)
{
  __shared__ __align__(16) unsigned short KV[4][64*64];   // 32 KB (sweep 2 only)
  __shared__ __align__(16) unsigned short Ps[64*64];      // 8 KB  (flag, then P in sweep 2)
  const int tid = threadIdx.x, lane = tid & 63, wave = tid >> 6;
  const int lcol = lane & 15, lgrp = lane >> 4;
  // XCD-aware mapping: blocks with same id%8 (same XCD) share bh => K/V L2-resident.
  const int id = blockIdx.x;                 // 2048 = 8 xcd * 8 bh * 32 qt
  const int sub = id >> 3;                   // 0..255
  const int bh = (id & 7)*8 + (sub >> 5);
  const int qt = sub & 31;
  const int b = bh >> 4;
  const int q0 = qt * 64;

  const unsigned short* Kbase = Kbh + ((size_t)bh*T_) * DK_;
  const unsigned short* Vbase = Vt + (size_t)bh*DK_*T_;

  // ---- mask all-ones precheck (cooperative, flag aliased into Ps) ----
  bool mall;
  {
    int* flag = (int*)Ps;
    const ulonglong2* mp = (const ulonglong2*)(mbits + ((size_t)b*T_ + q0)*32) + tid*4;
    unsigned long long macc = ~0ull;
#pragma unroll
    for (int i=0;i<4;i++){ ulonglong2 v = mp[i]; macc &= v.x & v.y; }
    if (tid == 0) *flag = 1;
    __syncthreads();
    if (!__all(macc == ~0ull) && (lane == 0)) atomicAnd(flag, 0);
    __syncthreads();
    mall = (*flag != 0);
    WAITL0();                    // flag ds_read retired before Ps reused (sweep 2)
  }

  // Q fragments: direct from global (one-time, 2 x 16B per lane)
  const int qr = wave*16 + lcol;                 // this lane's q row (block-local)
  bf16x8 qf[2];
  {
    const unsigned short* qrow = Qbh + ((size_t)bh*T_ + q0 + qr)*DK_ + lgrp*8;
    qf[0] = *(const bf16x8*)(qrow);
    qf[1] = *(const bf16x8*)(qrow + 32);
  }

  const unsigned long long* mrp = mbits + ((size_t)b*T_ + q0 + qr)*32;
  const int bit0 = lgrp*4;

  float lsum = 0.f;

  // ---- sweep 1: l = sum(exp2(s_masked)); K direct from global, zero barriers ----
  // fragment(kb,kh) @ kv = K[(kv*64 + kb*16 + lcol)*64 + kh*32 + lgrp*8 .. +7]
  const unsigned short* kp0 = Kbase + (size_t)lcol*DK_ + lgrp*8;
  if (mall){
#pragma unroll 2
    for (int kv=0; kv<32; ++kv){
      const unsigned short* kp = kp0 + (size_t)kv*64*DK_;
      bf16x8 kf[2][4];
#pragma unroll
      for (int kh=0;kh<2;kh++)
#pragma unroll
        for (int kb=0;kb<4;kb++)
          kf[kh][kb] = *(const bf16x8*)(kp + kb*16*DK_ + kh*32);
      f32x4 sf[4] = {};
#pragma unroll
      for (int kh=0;kh<2;kh++)
#pragma unroll
        for (int kb=0;kb<4;kb++)
          sf[kb] = mfma16(kf[kh][kb], qf[kh], sf[kb]);
      float part = 0.f;
#pragma unroll
      for (int kb=0;kb<4;kb++)
#pragma unroll
        for (int r=0;r<4;r++) part += fexp2(sf[kb][r]);
      lsum += part;
    }
  } else {
#pragma unroll 2
    for (int kv=0; kv<32; ++kv){
      const unsigned short* kp = kp0 + (size_t)kv*64*DK_;
      bf16x8 kf[2][4];
#pragma unroll
      for (int kh=0;kh<2;kh++)
#pragma unroll
        for (int kb=0;kb<4;kb++)
          kf[kh][kb] = *(const bf16x8*)(kp + kb*16*DK_ + kh*32);
      f32x4 sf[4] = {};
#pragma unroll
      for (int kh=0;kh<2;kh++)
#pragma unroll
        for (int kb=0;kb<4;kb++)
          sf[kb] = mfma16(kf[kh][kb], qf[kh], sf[kb]);
      unsigned long long w = mrp[kv];
      float part = 0.f;
#pragma unroll
      for (int kb=0;kb<4;kb++)
#pragma unroll
        for (int r=0;r<4;r++)
          part += fexp2(((w >> (kb*16 + bit0 + r)) & 1ull) ? sf[kb][r] : NEGF);
      lsum += part;
    }
  }

  // merge l across the 4 lane-groups sharing each q row
  lsum += __shfl_xor(lsum, 16);
  lsum += __shfl_xor(lsum, 32);
  const float mmr = (lsum > 0.f) ? __log2f(lsum) : 3.0e38f;   // p = exp2(s - mmr)

  f32x4 oacc[4] = {};
  float* abase = attn + ((size_t)bh*T_ + q0)*T_;

  // ---- sweep 2: recompute S^T, write attn (nt), P->LDS, PV ----
  unsigned short* const Ks0 = KV[0];
  unsigned short* const Ks1 = KV[1];
  unsigned short* const Vt0 = KV[2];
  unsigned short* const Vt1 = KV[3];
  stage_gl64(Kbase, 64, Ks0, wave, lane);
  stage_gl64(Vbase, T_, Vt0, wave, lane);

  if (mall){
    WAITV0(); SCHEDB(); SBAR();
#pragma unroll 1
    for (int kv=0; kv<32; ++kv){
      if (kv < 31){
        stage_gl64(Kbase + (size_t)(kv+1)*64*DK_, 64, (kv&1) ? Ks0 : Ks1, wave, lane);
        stage_gl64(Vbase + (size_t)(kv+1)*64, T_, (kv&1) ? Vt0 : Vt1, wave, lane);
      }
      FENCE(); SCHEDB();                      // pin: gloads issue before stores below
      const unsigned short* kcur = (kv&1) ? Ks1 : Ks0;
      f32x4 sf[4] = {};
      __builtin_amdgcn_s_setprio(1);
#pragma unroll
      for (int kh=0;kh<2;kh++)
#pragma unroll
        for (int kb=0;kb<4;kb++)
          sf[kb] = mfma16(lds_frag(kcur, kb*16 + lcol, kh*4 + lgrp), qf[kh], sf[kb]);
      __builtin_amdgcn_s_setprio(0);
      float* arow = abase + (size_t)qr*T_ + kv*64 + bit0;
      char* prow = (char*)Ps + qr*128 + ((lgrp & 1) << 3);
      const int sw = qr & 7;
#pragma unroll
      for (int kb=0;kb<4;kb++){
        float p0 = fexp2(sf[kb][0] - mmr);
        float p1 = fexp2(sf[kb][1] - mmr);
        float p2 = fexp2(sf[kb][2] - mmr);
        float p3 = fexp2(sf[kb][3] - mmr);
        f32x4 st = {p0, p1, p2, p3};
        __builtin_nontemporal_store(st, (f32x4*)(arow + kb*16));
        uint2 pb;
        pb.x = pk2(p0, p1);
        pb.y = pk2(p2, p3);
        *(uint2*)(prow + ((((kb << 1) | (lgrp >> 1)) ^ sw) << 4)) = pb;
      }
      WAITL0(); SCHEDB(); SBAR();             // Ps published; own QK ds_reads done
      const unsigned short* vcur = (kv&1) ? Vt1 : Vt0;
      __builtin_amdgcn_s_setprio(1);
#pragma unroll
      for (int kh=0;kh<2;kh++){
        bf16x8 af = lds_frag(vcur, wave*16 + lcol, kh*4 + lgrp);
#pragma unroll
        for (int qb=0;qb<4;qb++)
          oacc[qb] = mfma16(af, lds_frag(Ps, qb*16 + lcol, kh*4 + lgrp), oacc[qb]);
      }
      __builtin_amdgcn_s_setprio(0);
      // own PV ds_reads done; own gloads_{kv+1} retired (4 newer stores may fly)
      WAITLV4(); SCHEDB(); SBAR();
    }
  } else {
    __syncthreads();
#pragma unroll 1
    for (int kv=0; kv<32; ++kv){
      if (kv < 31){
        stage_gl64(Kbase + (size_t)(kv+1)*64*DK_, 64, (kv&1) ? Ks0 : Ks1, wave, lane);
        stage_gl64(Vbase + (size_t)(kv+1)*64, T_, (kv&1) ? Vt0 : Vt1, wave, lane);
      }
      unsigned long long w = mrp[kv];
      const unsigned short* kcur = (kv&1) ? Ks1 : Ks0;
      f32x4 sf[4] = {};
#pragma unroll
      for (int kh=0;kh<2;kh++)
#pragma unroll
        for (int kb=0;kb<4;kb++)
          sf[kb] = mfma16(lds_frag(kcur, kb*16 + lcol, kh*4 + lgrp), qf[kh], sf[kb]);
      float* arow = abase + (size_t)qr*T_ + kv*64 + bit0;
      char* prow = (char*)Ps + qr*128 + ((lgrp & 1) << 3);
      const int sw = qr & 7;
#pragma unroll
      for (int kb=0;kb<4;kb++){
        float p0 = fexp2(sf[kb][0] - mmr);
        float p1 = fexp2(sf[kb][1] - mmr);
        float p2 = fexp2(sf[kb][2] - mmr);
        float p3 = fexp2(sf[kb][3] - mmr);
        p0 = ((w >> (kb*16 + bit0    )) & 1ull) ? p0 : 0.f;
        p1 = ((w >> (kb*16 + bit0 + 1)) & 1ull) ? p1 : 0.f;
        p2 = ((w >> (kb*16 + bit0 + 2)) & 1ull) ? p2 : 0.f;
        p3 = ((w >> (kb*16 + bit0 + 3)) & 1ull) ? p3 : 0.f;
        f32x4 st = {p0, p1, p2, p3};
        __builtin_nontemporal_store(st, (f32x4*)(arow + kb*16));
        uint2 pb;
        pb.x = pk2(p0, p1);
        pb.y = pk2(p2, p3);
        *(uint2*)(prow + ((((kb << 1) | (lgrp >> 1)) ^ sw) << 4)) = pb;
      }
      __syncthreads();
      const unsigned short* vcur = (kv&1) ? Vt1 : Vt0;
#pragma unroll
      for (int kh=0;kh<2;kh++){
        bf16x8 af = lds_frag(vcur, wave*16 + lcol, kh*4 + lgrp);
#pragma unroll
        for (int qb=0;qb<4;qb++)
          oacc[qb] = mfma16(af, lds_frag(Ps, qb*16 + lcol, kh*4 + lgrp), oacc[qb]);
      }
      __syncthreads();
    }
  }

  // ---- epilogue: O^T fragments -> LDS transpose (reuse KV[0..1]) -> coalesced Xq ----
  unsigned short* Es = KV[0];    // 64 x 68 shorts = 8.7 KB
#pragma unroll
  for (int qb=0;qb<4;qb++){
    uint2 pv;
    pv.x = pk2(oacc[qb][0], oacc[qb][1]);
    pv.y = pk2(oacc[qb][2], oacc[qb][3]);
    *(uint2*)(Es + (qb*16 + lcol)*68 + wave*16 + lgrp*4) = pv;
  }
  __syncthreads();
  unsigned short* xrow = Xq + ((size_t)bh*T_ + q0)*DK_;
#pragma unroll
  for (int it=0; it<4; ++it){
    int idx = tid + it*256;
    int q = idx >> 4, sl = idx & 15;
    uint2 v = *(const uint2*)(Es + q*68 + sl*4);
    *(uint2*)(xrow + (size_t)q*64 + sl*4) = v;
  }
}

extern "C" void kernel_launch(void* const* d_in, const int* in_sizes, int n_in,
                              void* d_out, int out_size, void* d_ws, size_t ws_size,
                              hipStream_t stream) {
  const float* query = (const float*)d_in[0];
  const float* key   = (const float*)d_in[1];
  const float* value = (const float*)d_in[2];
  const int*   mask  = (const int*)d_in[3];
  const float* Wq = (const float*)d_in[4];  const float* bq = (const float*)d_in[5];
  const float* Wk = (const float*)d_in[6];  const float* bk = (const float*)d_in[7];
  const float* Wv = (const float*)d_in[8];  const float* bv = (const float*)d_in[9];
  const float* Wo = (const float*)d_in[10]; const float* bo = (const float*)d_in[11];

  float* out  = (float*)d_out;
  float* attn = out + (size_t)B_*T_*D_;

  char* ws = (char*)d_ws;
  unsigned short* Qbh = (unsigned short*)(ws);                       // 16 MiB (reused as Xq)
  unsigned short* Kbh = (unsigned short*)(ws + ((size_t)16<<20));    // 16 MiB (Qbh+8388608)
  unsigned short* Vt  = (unsigned short*)(ws + ((size_t)32<<20));    // 16 MiB
  unsigned long long* mb = (unsigned long long*)(ws + ((size_t)48<<20)); // 2 MiB
  unsigned short* Wbf = (unsigned short*)(ws + ((size_t)50<<20));    // 8 MiB (Wq,Wk,Wv,Wo)
  // bf16 copies of query/key/value live in the attn OUTPUT region (written later by attn_k)
  unsigned short* Xbf = (unsigned short*)attn;                       // 48 MiB scratch

  pack_mask_k<<<dim3((B_*T_*T_)/256), 256, 0, stream>>>(mask, mb);
  convall_k<<<dim3(14336), 256, 0, stream>>>(Wq, Wk, Wv, Wo, query, key, value, Wbf, Xbf);
  // unified Q + K + Vt projections: 1536 blocks = exactly 2 full waves at 3 blocks/CU
  gemm_in<<<dim3(1536), 256, 0, stream>>>(Xbf, Wbf, bq, bk, bv, Qbh, Vt);
  attn_k<<<dim3(2048), 256, 0, stream>>>(Qbh, Kbh, Vt, mb, attn, Qbh);
  gemm_out<<<dim3(8,64), 256, 0, stream>>>(Qbh, Wbf + (3u<<20), bo, out);
}

// Round 15
// 432.006 us; speedup vs baseline: 1.1897x; 1.1897x over previous
//
#include <hip/hip_runtime.h>
#include <hip/hip_bf16.h>
#include <stdint.h>

#define B_ 4
#define T_ 2048
#define D_ 1024
#define H_ 16
#define DK_ 64
#define LOG2E 1.44269504088896340736f
#define NEGF (-3.0e38f)

typedef __attribute__((ext_vector_type(8))) short bf16x8;
typedef __attribute__((ext_vector_type(4))) float f32x4;

#define FENCE()   asm volatile("" ::: "memory")
#define SCHEDB()  __builtin_amdgcn_sched_barrier(0)
#define SBAR()    __builtin_amdgcn_s_barrier()
#define WAITV0()  asm volatile("s_waitcnt vmcnt(0)" ::: "memory")
#define WAITV2()  asm volatile("s_waitcnt vmcnt(2)" ::: "memory")
#define WAITV4()  asm volatile("s_waitcnt vmcnt(4)" ::: "memory")
#define WAITV6()  asm volatile("s_waitcnt vmcnt(6)" ::: "memory")
#define WAITL0()  asm volatile("s_waitcnt lgkmcnt(0)" ::: "memory")
#define WAITLV4() asm volatile("s_waitcnt lgkmcnt(0) vmcnt(4)" ::: "memory")

// compiler-native bf16 convert (lowers to v_cvt_pk_bf16_f32 when paired)
__device__ inline unsigned short f2bf(float f){
  union { __hip_bfloat16 h; unsigned short u; } v;
  v.h = __hip_bfloat16(f);
  return v.u;
}
__device__ inline unsigned int pk2(float a, float b){
  return (unsigned int)f2bf(a) | ((unsigned int)f2bf(b) << 16);
}
__device__ inline float fexp2(float x){ return __builtin_amdgcn_exp2f(x); }
__device__ inline f32x4 mfma16(bf16x8 a, bf16x8 b, f32x4 c){
  return __builtin_amdgcn_mfma_f32_16x16x32_bf16(a, b, c, 0, 0, 0);
}
// LDS tile rows = 64 bf16 = 128B = 8 chunks of 16B, chunk swizzle: phys = logical ^ (row&7)
__device__ inline bf16x8 lds_frag(const unsigned short* base, int row, int slot){
  return *(const bf16x8*)((const char*)base + row*128 + ((slot ^ (row & 7)) << 4));
}
// async global->LDS, 16B per lane. LDS dest = wave-uniform base + lane*16 (linear).
__device__ inline void gload16(const void* g, void* l){
  __builtin_amdgcn_global_load_lds((const __attribute__((address_space(1))) void*)g,
                                   (__attribute__((address_space(3))) void*)l, 16, 0, 0);
}
// 128x64 bf16 tile: wave stages 32 rows (4 instrs x 8 rows). Source chunk pre-swizzled.
__device__ inline void stage_gl128(const unsigned short* __restrict__ g, int ld,
                                   unsigned short* lds, int wave, int lane){
#pragma unroll
  for (int i = 0; i < 4; ++i){
    int row = wave*32 + i*8 + (lane >> 3);
    int c = (lane & 7) ^ (row & 7);
    gload16(g + (size_t)row*ld + c*8, lds + (wave*32 + i*8)*64);
  }
}
// 64x64 bf16 tile: wave stages 16 rows (2 VMEM instrs x 8 rows).
__device__ inline void stage_gl64(const unsigned short* __restrict__ g, int ld,
                                  unsigned short* lds, int wave, int lane){
#pragma unroll
  for (int i = 0; i < 2; ++i){
    int row = wave*16 + i*8 + (lane >> 3);
    int c = (lane & 7) ^ (row & 7);
    gload16(g + (size_t)row*ld + c*8, lds + (wave*16 + i*8)*64);
  }
}

// ---------------- mask pack: (B,T,T) int32 -> bitmask u64 ----------------
__global__ void pack_mask_k(const int* __restrict__ mask, unsigned long long* __restrict__ bits){
  int i = blockIdx.x * 256 + threadIdx.x;
  unsigned long long b = __ballot(mask[i] != 0);
  if ((threadIdx.x & 63) == 0) bits[i >> 6] = b;
}

// ---------------- fused fp32->bf16: weights (4x1M) + inputs (3x8M) ----------------
__global__ void convall_k(const float* __restrict__ Wq, const float* __restrict__ Wk,
                          const float* __restrict__ Wv, const float* __restrict__ Wo,
                          const float* __restrict__ q, const float* __restrict__ k,
                          const float* __restrict__ v,
                          unsigned short* __restrict__ wdst, unsigned short* __restrict__ xdst){
  int g = blockIdx.x*256 + threadIdx.x;     // 14336 blocks x 256
  const float* s; unsigned short* d; int off;
  if (g < 524288){
    int w = g >> 17; off = (g & 131071) * 8;
    s = (w==0) ? Wq : (w==1) ? Wk : (w==2) ? Wv : Wo;
    d = wdst + (size_t)w*1048576 + off;
  } else {
    int gg = g - 524288;
    int w = gg >> 20; off = (gg & 1048575) * 8;
    s = (w==0) ? q : (w==1) ? k : v;
    d = xdst + (size_t)w*8388608 + off;
  }
  float4 a = *(const float4*)(s + off);
  float4 b2 = *(const float4*)(s + off + 4);
  uint4 o;
  o.x = pk2(a.x,a.y); o.y = pk2(a.z,a.w); o.z = pk2(b2.x,b2.y); o.w = pk2(b2.z,b2.w);
  *(uint4*)d = o;
}

// ---------------- unified input GEMMs: Q, K + Vt, 1536 blocks (2 full waves @3/CU) ----------------
__global__ __launch_bounds__(256, 3)
void gemm_in(const unsigned short* __restrict__ Xbf, const unsigned short* __restrict__ Wbf,
             const float* __restrict__ bq, const float* __restrict__ bk,
             const float* __restrict__ bv,
             unsigned short* __restrict__ QKout, unsigned short* __restrict__ Vt)
{
  __shared__ __align__(16) unsigned short As[128*64];
  __shared__ __align__(16) unsigned short Bs[128*64];
  const int tid = threadIdx.x, lane = tid & 63, wave = tid >> 6;
  const int lcol = lane & 15, lgrp = lane >> 4;
  const int id = blockIdx.x;
  const bool vmode = (id >= 1024);
  int mtile, ntile;
  const unsigned short *A, *W;
  if (!vmode){
    int z = id >> 9, rem = id & 511;
    mtile = rem >> 3; ntile = rem & 7;
    A = Xbf + (size_t)z*8388608;
    W = Wbf + (size_t)z*1048576;
  } else {
    int rem = id - 1024;
    mtile = rem >> 6; ntile = rem & 63;
    A = Wbf + (size_t)2*1048576;      // Wv
    W = Xbf + (size_t)2*8388608;      // value_bf
  }
  const int wm = (wave & 1) * 64, wn = (wave >> 1) * 64;
  f32x4 acc[4][4] = {};
#pragma unroll 1
  for (int kt = 0; kt < 16; ++kt){
    stage_gl128(A + (size_t)(mtile*128)*1024 + kt*64, 1024, As, wave, lane);
    stage_gl128(W + (size_t)(ntile*128)*1024 + kt*64, 1024, Bs, wave, lane);
    __syncthreads();
    bf16x8 af[4][2], bfr[4][2];
#pragma unroll
    for (int mi=0;mi<4;mi++)
#pragma unroll
      for (int kh=0;kh<2;kh++)
        af[mi][kh] = lds_frag(As, wm + mi*16 + lcol, kh*4 + lgrp);
#pragma unroll
    for (int ni=0;ni<4;ni++)
#pragma unroll
      for (int kh=0;kh<2;kh++)
        bfr[ni][kh] = lds_frag(Bs, wn + ni*16 + lcol, kh*4 + lgrp);
    __builtin_amdgcn_s_setprio(1);
#pragma unroll
    for (int mi=0;mi<4;mi++)
#pragma unroll
      for (int ni=0;ni<4;ni++)
#pragma unroll
        for (int kh=0;kh<2;kh++)
          acc[mi][ni] = mfma16(af[mi][kh], bfr[ni][kh], acc[mi][ni]);
    __builtin_amdgcn_s_setprio(0);
    __syncthreads();
  }
  if (!vmode){
    int z = id >> 9;
    const float* bias = z ? bk : bq;
    unsigned short* C = QKout + (size_t)z*8388608;
    float osc = z ? 1.0f : 0.125f*LOG2E;
#pragma unroll
    for (int mi=0;mi<4;mi++)
#pragma unroll
      for (int ni=0;ni<4;ni++){
        int n = ntile*128 + wn + ni*16 + lcol;
#pragma unroll
        for (int r=0;r<4;r++){
          int m = mtile*128 + wm + mi*16 + lgrp*4 + r;
          float v = (acc[mi][ni][r] + bias[n]) * osc;
          int bb = m >> 11, t = m & 2047, hh = n >> 6, dk = n & 63;
          C[(((size_t)(bb*H_ + hh)*T_ + t) << 6) + dk] = f2bf(v);
        }
      }
  } else {
#pragma unroll
    for (int mi=0;mi<4;mi++)
#pragma unroll
      for (int ni=0;ni<4;ni++){
        int n = ntile*128 + wn + ni*16 + lcol;
#pragma unroll
        for (int r=0;r<4;r++){
          int m = mtile*128 + wm + mi*16 + lgrp*4 + r;
          float v = acc[mi][ni][r] + bv[m];
          int bb = n >> 11, t = n & 2047, hh = m >> 6, dk = m & 63;
          Vt[(((size_t)(bb*H_ + hh)*DK_ + dk) << 11) + t] = f2bf(v);
        }
      }
  }
}

// ---------------- out GEMM: out[8192][1024] = Xq(B,H,T,DK) @ Wo^T + bo (fp32 out) ----------------
__global__ __launch_bounds__(256, 3)
void gemm_out(const unsigned short* __restrict__ A, const unsigned short* __restrict__ W,
              const float* __restrict__ bias, float* __restrict__ C)
{
  __shared__ __align__(16) unsigned short As[128*64];
  __shared__ __align__(16) unsigned short Bs[128*64];
  const int tid = threadIdx.x, lane = tid & 63, wave = tid >> 6;
  const int lcol = lane & 15, lgrp = lane >> 4;
  const int mtile = blockIdx.y, ntile = blockIdx.x;
  const int wm = (wave & 1) * 64, wn = (wave >> 1) * 64;
  f32x4 acc[4][4] = {};
#pragma unroll 1
  for (int kt = 0; kt < 16; ++kt){
    int m0 = mtile*128; int b = m0 >> 11; int t0 = m0 & 2047;
    const unsigned short* xbase = A + (((size_t)(b*16 + kt)*2048 + t0) << 6);
    stage_gl128(xbase, 64, As, wave, lane);
    stage_gl128(W + (size_t)(ntile*128)*1024 + kt*64, 1024, Bs, wave, lane);
    __syncthreads();
    bf16x8 af[4][2], bfr[4][2];
#pragma unroll
    for (int mi=0;mi<4;mi++)
#pragma unroll
      for (int kh=0;kh<2;kh++)
        af[mi][kh] = lds_frag(As, wm + mi*16 + lcol, kh*4 + lgrp);
#pragma unroll
    for (int ni=0;ni<4;ni++)
#pragma unroll
      for (int kh=0;kh<2;kh++)
        bfr[ni][kh] = lds_frag(Bs, wn + ni*16 + lcol, kh*4 + lgrp);
    __builtin_amdgcn_s_setprio(1);
#pragma unroll
    for (int mi=0;mi<4;mi++)
#pragma unroll
      for (int ni=0;ni<4;ni++)
#pragma unroll
        for (int kh=0;kh<2;kh++)
          acc[mi][ni] = mfma16(af[mi][kh], bfr[ni][kh], acc[mi][ni]);
    __builtin_amdgcn_s_setprio(0);
    __syncthreads();
  }
#pragma unroll
  for (int mi=0;mi<4;mi++)
#pragma unroll
    for (int ni=0;ni<4;ni++){
      int n = ntile*128 + wn + ni*16 + lcol;
#pragma unroll
      for (int r=0;r<4;r++){
        int m = mtile*128 + wm + mi*16 + lgrp*4 + r;
        C[(size_t)m*D_ + n] = acc[mi][ni][r] + bias[n];
      }
    }
}

// ---------------- fused attention (R11 base + coalesced-permuted attn stores) ----------------
// Sweep 1: 4-deep K ring, counted vmcnt(6). Sweep 2: K/V dbuf, nt stores with
// __shfl lane-permute so lanes 4r..4r+3 write one contiguous 64B line (kills the
// 38% partial-line write amplification R11 measured: WRITE 1.47e6 -> ~1.09e6 KB).
__global__ __launch_bounds__(256, 4)
void attn_k(const unsigned short* __restrict__ Qbh, const unsigned short* __restrict__ Kbh,
            const unsigned short* __restrict__ Vt, const unsigned long long* __restrict__ mbits,
            float* __restrict__ attn, unsigned short* __restrict__ Xq)
{
  __shared__ __align__(16) unsigned short KV[4][64*64];   // 32 KB: S1 K-ring; S2 Ks=KV[0,1], Vts=KV[2,3]
  __shared__ __align__(16) unsigned short Ps[64*64];      // 8 KB  (Q at prologue, P in sweep 2)
  __shared__ int s_mall;
  const int tid = threadIdx.x, lane = tid & 63, wave = tid >> 6;
  const int lcol = lane & 15, lgrp = lane >> 4;
  // XCD-aware mapping: blocks with same id%8 (same XCD) share bh => K/V L2-resident.
  const int id = blockIdx.x;                 // 2048 = 8 xcd * 8 bh * 32 qt
  const int sub = id >> 3;                   // 0..255
  const int bh = (id & 7)*8 + (sub >> 5);
  const int qt = sub & 31;
  const int b = bh >> 4;
  const int q0 = qt * 64;

  const unsigned short* Kbase = Kbh + ((size_t)bh*T_) * DK_;
  const unsigned short* Vbase = Vt + (size_t)bh*DK_*T_;

  // ---- mask all-ones precheck over this block's 64 rows (2048 u64 words) ----
  {
    const ulonglong2* mp = (const ulonglong2*)(mbits + ((size_t)b*T_ + q0)*32) + tid*4;
    unsigned long long macc = ~0ull;
#pragma unroll
    for (int i=0;i<4;i++){ ulonglong2 v = mp[i]; macc &= v.x & v.y; }
    if (tid == 0) s_mall = 1;
    __syncthreads();
    if (!__all(macc == ~0ull) && (lane == 0)) atomicAnd(&s_mall, 0);
  }

  // prologue: Q tile into Ps, K0..K2 into ring
  stage_gl64(Qbh + ((size_t)bh*T_ + q0)*DK_, 64, Ps, wave, lane);
  stage_gl64(Kbase,             64, KV[0], wave, lane);
  stage_gl64(Kbase + 64*DK_,    64, KV[1], wave, lane);
  stage_gl64(Kbase + 2*64*DK_,  64, KV[2], wave, lane);
  __syncthreads();                      // drains prologue staging; publishes s_mall
  const bool mall = (s_mall != 0);
  bf16x8 qf[2];
#pragma unroll
  for (int kh=0;kh<2;kh++) qf[kh] = lds_frag(Ps, wave*16 + lcol, kh*4 + lgrp);

  const int qr = wave*16 + lcol;                 // this lane's q row (block-local)
  const unsigned long long* mrp = mbits + ((size_t)b*T_ + q0 + qr)*32;
  const int bit0 = lgrp*4;

  float lsum = 0.f;

  // ---- sweep 1: l = sum(exp2(s_masked)) (log2e folded into Q proj) ----
  if (mall){
#pragma unroll 1
    for (int kv=0; kv<29; ++kv){
      stage_gl64(Kbase + (size_t)(kv+3)*64*DK_, 64, KV[(kv+3)&3], wave, lane);
      WAITV6(); SCHEDB(); SBAR();
      const unsigned short* kcur = KV[kv&3];
      f32x4 sf[4] = {};
      __builtin_amdgcn_s_setprio(1);
#pragma unroll
      for (int kh=0;kh<2;kh++)
#pragma unroll
        for (int kb=0;kb<4;kb++)
          sf[kb] = mfma16(lds_frag(kcur, kb*16 + lcol, kh*4 + lgrp), qf[kh], sf[kb]);
      __builtin_amdgcn_s_setprio(0);
      float part = 0.f;
#pragma unroll
      for (int kb=0;kb<4;kb++)
#pragma unroll
        for (int r=0;r<4;r++) part += fexp2(sf[kb][r]);
      lsum += part;
      WAITL0(); SCHEDB(); SBAR();
    }
#pragma unroll 1
    for (int kv=29; kv<32; ++kv){
      if (kv == 29) { WAITV4(); } else if (kv == 30) { WAITV2(); } else { WAITV0(); }
      SCHEDB(); SBAR();
      const unsigned short* kcur = KV[kv&3];
      f32x4 sf[4] = {};
      __builtin_amdgcn_s_setprio(1);
#pragma unroll
      for (int kh=0;kh<2;kh++)
#pragma unroll
        for (int kb=0;kb<4;kb++)
          sf[kb] = mfma16(lds_frag(kcur, kb*16 + lcol, kh*4 + lgrp), qf[kh], sf[kb]);
      __builtin_amdgcn_s_setprio(0);
      float part = 0.f;
#pragma unroll
      for (int kb=0;kb<4;kb++)
#pragma unroll
        for (int r=0;r<4;r++) part += fexp2(sf[kb][r]);
      lsum += part;
      WAITL0(); SCHEDB(); SBAR();
    }
  } else {
#pragma unroll 1
    for (int kv=0; kv<32; ++kv){
      if (kv < 31) stage_gl64(Kbase + (size_t)(kv+1)*64*DK_, 64, KV[(kv+1)&1], wave, lane);
      const unsigned short* kcur = KV[kv&1];
      f32x4 sf[4] = {};
#pragma unroll
      for (int kh=0;kh<2;kh++)
#pragma unroll
        for (int kb=0;kb<4;kb++)
          sf[kb] = mfma16(lds_frag(kcur, kb*16 + lcol, kh*4 + lgrp), qf[kh], sf[kb]);
      unsigned long long w = mrp[kv];
      float part = 0.f;
#pragma unroll
      for (int kb=0;kb<4;kb++)
#pragma unroll
        for (int r=0;r<4;r++)
          part += fexp2(((w >> (kb*16 + bit0 + r)) & 1ull) ? sf[kb][r] : NEGF);
      lsum += part;
      __syncthreads();
    }
  }

  // merge l across the 4 lane-groups sharing each q row
  lsum += __shfl_xor(lsum, 16);
  lsum += __shfl_xor(lsum, 32);
  const float mmr = (lsum > 0.f) ? __log2f(lsum) : 3.0e38f;   // p = exp2(s - mmr)

  f32x4 oacc[4] = {};
  float* abase = attn + ((size_t)bh*T_ + q0)*T_;
  // permuted-store geometry: lane l writes row (l>>2), 16B chunk j=(l&3) of each 64B seg
  const int srcl = (lane & 3)*16 + (lane >> 2);
  float* arow2base = abase + (size_t)(wave*16 + (lane>>2))*T_ + (lane&3)*4;

  // ---- sweep 2: recompute S^T, write attn (nt, permuted-coalesced), P->LDS, PV ----
  unsigned short* const Ks0 = KV[0];
  unsigned short* const Ks1 = KV[1];
  unsigned short* const Vt0 = KV[2];
  unsigned short* const Vt1 = KV[3];
  stage_gl64(Kbase, 64, Ks0, wave, lane);
  stage_gl64(Vbase, T_, Vt0, wave, lane);

  if (mall){
    WAITV0(); SCHEDB(); SBAR();
#pragma unroll 1
    for (int kv=0; kv<32; ++kv){
      if (kv < 31){
        stage_gl64(Kbase + (size_t)(kv+1)*64*DK_, 64, (kv&1) ? Ks0 : Ks1, wave, lane);
        stage_gl64(Vbase + (size_t)(kv+1)*64, T_, (kv&1) ? Vt0 : Vt1, wave, lane);
      }
      FENCE(); SCHEDB();                      // pin: gloads issue before stores below
      const unsigned short* kcur = (kv&1) ? Ks1 : Ks0;
      f32x4 sf[4] = {};
      __builtin_amdgcn_s_setprio(1);
#pragma unroll
      for (int kh=0;kh<2;kh++)
#pragma unroll
        for (int kb=0;kb<4;kb++)
          sf[kb] = mfma16(lds_frag(kcur, kb*16 + lcol, kh*4 + lgrp), qf[kh], sf[kb]);
      __builtin_amdgcn_s_setprio(0);
      char* prow = (char*)Ps + qr*128 + ((lgrp & 1) << 3);
      const int sw = qr & 7;
      float pe[4][4];
#pragma unroll
      for (int kb=0;kb<4;kb++){
        pe[kb][0] = fexp2(sf[kb][0] - mmr);
        pe[kb][1] = fexp2(sf[kb][1] - mmr);
        pe[kb][2] = fexp2(sf[kb][2] - mmr);
        pe[kb][3] = fexp2(sf[kb][3] - mmr);
        uint2 pb;
        pb.x = pk2(pe[kb][0], pe[kb][1]);
        pb.y = pk2(pe[kb][2], pe[kb][3]);
        *(uint2*)(prow + ((((kb << 1) | (lgrp >> 1)) ^ sw) << 4)) = pb;
      }
      // lane-permute so 4 consecutive lanes cover one contiguous 64B line
      float* arow2 = arow2base + kv*64;
#pragma unroll
      for (int kb=0;kb<4;kb++){
        f32x4 st;
        st[0] = __shfl(pe[kb][0], srcl);
        st[1] = __shfl(pe[kb][1], srcl);
        st[2] = __shfl(pe[kb][2], srcl);
        st[3] = __shfl(pe[kb][3], srcl);
        __builtin_nontemporal_store(st, (f32x4*)(arow2 + kb*16));
      }
      WAITL0(); SCHEDB(); SBAR();             // Ps published; own QK ds_reads done
      const unsigned short* vcur = (kv&1) ? Vt1 : Vt0;
      __builtin_amdgcn_s_setprio(1);
#pragma unroll
      for (int kh=0;kh<2;kh++){
        bf16x8 af = lds_frag(vcur, wave*16 + lcol, kh*4 + lgrp);
#pragma unroll
        for (int qb=0;qb<4;qb++)
          oacc[qb] = mfma16(af, lds_frag(Ps, qb*16 + lcol, kh*4 + lgrp), oacc[qb]);
      }
      __builtin_amdgcn_s_setprio(0);
      // own PV ds_reads done; own gloads_{kv+1} retired (4 newer stores may fly)
      WAITLV4(); SCHEDB(); SBAR();
    }
  } else {
    __syncthreads();
#pragma unroll 1
    for (int kv=0; kv<32; ++kv){
      if (kv < 31){
        stage_gl64(Kbase + (size_t)(kv+1)*64*DK_, 64, (kv&1) ? Ks0 : Ks1, wave, lane);
        stage_gl64(Vbase + (size_t)(kv+1)*64, T_, (kv&1) ? Vt0 : Vt1, wave, lane);
      }
      unsigned long long w = mrp[kv];
      const unsigned short* kcur = (kv&1) ? Ks1 : Ks0;
      f32x4 sf[4] = {};
#pragma unroll
      for (int kh=0;kh<2;kh++)
#pragma unroll
        for (int kb=0;kb<4;kb++)
          sf[kb] = mfma16(lds_frag(kcur, kb*16 + lcol, kh*4 + lgrp), qf[kh], sf[kb]);
      char* prow = (char*)Ps + qr*128 + ((lgrp & 1) << 3);
      const int sw = qr & 7;
      float pe[4][4];
#pragma unroll
      for (int kb=0;kb<4;kb++){
        float p0 = fexp2(sf[kb][0] - mmr);
        float p1 = fexp2(sf[kb][1] - mmr);
        float p2 = fexp2(sf[kb][2] - mmr);
        float p3 = fexp2(sf[kb][3] - mmr);
        p0 = ((w >> (kb*16 + bit0    )) & 1ull) ? p0 : 0.f;
        p1 = ((w >> (kb*16 + bit0 + 1)) & 1ull) ? p1 : 0.f;
        p2 = ((w >> (kb*16 + bit0 + 2)) & 1ull) ? p2 : 0.f;
        p3 = ((w >> (kb*16 + bit0 + 3)) & 1ull) ? p3 : 0.f;
        pe[kb][0]=p0; pe[kb][1]=p1; pe[kb][2]=p2; pe[kb][3]=p3;
        uint2 pb;
        pb.x = pk2(p0, p1);
        pb.y = pk2(p2, p3);
        *(uint2*)(prow + ((((kb << 1) | (lgrp >> 1)) ^ sw) << 4)) = pb;
      }
      float* arow2 = arow2base + kv*64;
#pragma unroll
      for (int kb=0;kb<4;kb++){
        f32x4 st;
        st[0] = __shfl(pe[kb][0], srcl);
        st[1] = __shfl(pe[kb][1], srcl);
        st[2] = __shfl(pe[kb][2], srcl);
        st[3] = __shfl(pe[kb][3], srcl);
        __builtin_nontemporal_store(st, (f32x4*)(arow2 + kb*16));
      }
      __syncthreads();
      const unsigned short* vcur = (kv&1) ? Vt1 : Vt0;
#pragma unroll
      for (int kh=0;kh<2;kh++){
        bf16x8 af = lds_frag(vcur, wave*16 + lcol, kh*4 + lgrp);
#pragma unroll
        for (int qb=0;qb<4;qb++)
          oacc[qb] = mfma16(af, lds_frag(Ps, qb*16 + lcol, kh*4 + lgrp), oacc[qb]);
      }
      __syncthreads();
    }
  }

  // ---- epilogue: O^T fragments -> LDS transpose (reuse KV[0..1]) -> coalesced Xq ----
  unsigned short* Es = KV[0];    // 64 x 68 shorts = 8.7 KB
#pragma unroll
  for (int qb=0;qb<4;qb++){
    uint2 pv;
    pv.x = pk2(oacc[qb][0], oacc[qb][1]);
    pv.y = pk2(oacc[qb][2], oacc[qb][3]);
    *(uint2*)(Es + (qb*16 + lcol)*68 + wave*16 + lgrp*4) = pv;
  }
  __syncthreads();
  unsigned short* xrow = Xq + ((size_t)bh*T_ + q0)*DK_;
#pragma unroll
  for (int it=0; it<4; ++it){
    int idx = tid + it*256;
    int q = idx >> 4, sl = idx & 15;
    uint2 v = *(const uint2*)(Es + q*68 + sl*4);
    *(uint2*)(xrow + (size_t)q*64 + sl*4) = v;
  }
}

extern "C" void kernel_launch(void* const* d_in, const int* in_sizes, int n_in,
                              void* d_out, int out_size, void* d_ws, size_t ws_size,
                              hipStream_t stream) {
  const float* query = (const float*)d_in[0];
  const float* key   = (const float*)d_in[1];
  const float* value = (const float*)d_in[2];
  const int*   mask  = (const int*)d_in[3];
  const float* Wq = (const float*)d_in[4];  const float* bq = (const float*)d_in[5];
  const float* Wk = (const float*)d_in[6];  const float* bk = (const float*)d_in[7];
  const float* Wv = (const float*)d_in[8];  const float* bv = (const float*)d_in[9];
  const float* Wo = (const float*)d_in[10]; const float* bo = (const float*)d_in[11];

  float* out  = (float*)d_out;
  float* attn = out + (size_t)B_*T_*D_;

  char* ws = (char*)d_ws;
  unsigned short* Qbh = (unsigned short*)(ws);                       // 16 MiB (reused as Xq)
  unsigned short* Kbh = (unsigned short*)(ws + ((size_t)16<<20));    // 16 MiB (Qbh+8388608)
  unsigned short* Vt  = (unsigned short*)(ws + ((size_t)32<<20));    // 16 MiB
  unsigned long long* mb = (unsigned long long*)(ws + ((size_t)48<<20)); // 2 MiB
  unsigned short* Wbf = (unsigned short*)(ws + ((size_t)50<<20));    // 8 MiB (Wq,Wk,Wv,Wo)
  // bf16 copies of query/key/value live in the attn OUTPUT region (written later by attn_k)
  unsigned short* Xbf = (unsigned short*)attn;                       // 48 MiB scratch

  pack_mask_k<<<dim3((B_*T_*T_)/256), 256, 0, stream>>>(mask, mb);
  convall_k<<<dim3(14336), 256, 0, stream>>>(Wq, Wk, Wv, Wo, query, key, value, Wbf, Xbf);
  // unified Q + K + Vt projections: 1536 blocks = exactly 2 full waves at 3 blocks/CU
  gemm_in<<<dim3(1536), 256, 0, stream>>>(Xbf, Wbf, bq, bk, bv, Qbh, Vt);
  attn_k<<<dim3(2048), 256, 0, stream>>>(Qbh, Kbh, Vt, mb, attn, Qbh);
  gemm_out<<<dim3(8,64), 256, 0, stream>>>(Qbh, Wbf + (3u<<20), bo, out);
}